// Round 1
// baseline (128.481 us; speedup 1.0000x reference)
//
#include <hip/hip_runtime.h>
#include <hip/hip_bf16.h>
#include <cstdint>

#define L_SEQ 16384
#define NST   512
#define HDIM  512
#define CH    256   // number of scan chunks
#define CT    64    // timesteps per chunk (CH*CT = L_SEQ)

typedef __attribute__((ext_vector_type(8))) short short8;
typedef __attribute__((ext_vector_type(4))) float f32x4;

static __device__ __forceinline__ ushort f2bf(float f) {
  union { float f; unsigned int u; } v; v.f = f;
  unsigned int r = v.u + 0x7fffu + ((v.u >> 16) & 1u);
  return (ushort)(r >> 16);
}
static __device__ __forceinline__ float bf2f(ushort u) {
  union { unsigned int u; float f; } v; v.u = ((unsigned int)u) << 16;
  return v.f;
}

static __device__ __forceinline__ void mfma_16x16x32_bf16(f32x4& d, short8 a, short8 b) {
  // inline asm avoids builtin signature ambiguity (short8 vs __bf16 vec);
  // "+v" ties C-in/D-out, hazard recognizer handles inline-asm MFMA defs.
  asm("v_mfma_f32_16x16x32_bf16 %0, %1, %2, %0" : "+v"(d) : "v"(a), "v"(b));
}

static __device__ __forceinline__ void gload_lds16(const ushort* g, ushort* l) {
  __builtin_amdgcn_global_load_lds((__attribute__((address_space(1))) void*)(g),
                                   (__attribute__((address_space(3))) void*)(l),
                                   16, 0, 0);
}

// ---------- prep: a = Lambda*state (per-step multiplier), aT = a^CT ----------
__global__ void prep_kernel(const float* __restrict__ st_re, const float* __restrict__ st_im,
                            const float* __restrict__ nu_log, const float* __restrict__ theta_log,
                            float2* __restrict__ lam, float2* __restrict__ lamT)
{
  int n = threadIdx.x;
  float nu  = expf(nu_log[n]);
  float th  = expf(theta_log[n]);
  float mag = expf(-nu);
  float lr = mag * cosf(th);
  float li = mag * sinf(th);
  float sr = st_re[n], si = st_im[n];
  float ar = lr * sr - li * si;
  float ai = lr * si + li * sr;
  lam[n] = make_float2(ar, ai);
  float pr = ar, pi = ai;
#pragma unroll
  for (int i = 0; i < 6; ++i) {        // a^(2^6) = a^CT, CT=64
    float nr = pr * pr - pi * pi;
    float ni = 2.f * pr * pi;
    pr = nr; pi = ni;
  }
  lamT[n] = make_float2(pr, pi);
}

// ---------- W1 = [Re(B*e^{ig}); Im(B*e^{ig})]  (1024 x 512) bf16 ----------
__global__ __launch_bounds__(256) void buildW1(const float* __restrict__ B_re,
                                               const float* __restrict__ B_im,
                                               const float* __restrict__ gamma_log,
                                               ushort* __restrict__ W1)
{
  int idx = blockIdx.x * 256 + threadIdx.x;   // n*512 + h
  int n = idx >> 9;
  int h = idx & 511;
  float g = gamma_log[n];
  float cg = cosf(g), sg = sinf(g);
  float br = B_re[idx], bi = B_im[idx];
  W1[(size_t)n * 512 + h]         = f2bf(br * cg - bi * sg);
  W1[(size_t)(n + 512) * 512 + h] = f2bf(br * sg + bi * cg);
}

// ---------- W2: (512 rows x 1024 k) bf16, W2[h, n]=C_re[h,n], W2[h, 512+n]=-C_im[h,n] ----------
__global__ __launch_bounds__(256) void buildW2(const float* __restrict__ C_re,
                                               const float* __restrict__ C_im,
                                               ushort* __restrict__ W2)
{
  int idx = blockIdx.x * 256 + threadIdx.x;   // hh*512 + n
  int hh = idx >> 9;
  int n = idx & 511;
  W2[(size_t)hh * 1024 + n]       = f2bf(C_re[idx]);
  W2[(size_t)hh * 1024 + 512 + n] = f2bf(-C_im[idx]);
}

// ---------- cast x (L,512) f32 -> bf16 ----------
__global__ __launch_bounds__(256) void castX(const float* __restrict__ X,
                                             ushort* __restrict__ xb)
{
  size_t i = ((size_t)blockIdx.x * 256 + threadIdx.x) * 8;
#pragma unroll
  for (int j = 0; j < 8; j += 4) {
    float4 v = *(const float4*)(X + i + j);
    ushort4 o;
    o.x = f2bf(v.x); o.y = f2bf(v.y); o.z = f2bf(v.z); o.w = f2bf(v.w);
    *(ushort4*)(xb + i + j) = o;
  }
}

// ---------- GEMM: C[m, j] = sum_k A[m,k] * B[j,k]; A (M x K) bf16, B (Ncols x K) bf16 ----------
// m97 structure: 128x128 tile, 4 waves (2x2), BK=32, global_load_lds w16, 2 barriers/K-step.
template <int EPI>
__global__ __launch_bounds__(256)
void gemm_bt(const ushort* __restrict__ A, const ushort* __restrict__ Bm,
             ushort* __restrict__ Cb, float* __restrict__ Cf,
             const float* __restrict__ Dv, const float* __restrict__ X,
             int M, int Ncols, int K)
{
  __shared__ __align__(16) ushort As[128 * 32];
  __shared__ __align__(16) ushort Bs[128 * 32];
  const int t    = threadIdx.x;
  const int lane = t & 63;
  const int w    = t >> 6;
  const int wr   = w >> 1, wc = w & 1;
  const int m0   = blockIdx.x * 128;
  const int n0   = blockIdx.y * 128;

  f32x4 acc[4][4];
#pragma unroll
  for (int i = 0; i < 4; ++i)
#pragma unroll
    for (int j = 0; j < 4; ++j) { f32x4 z = {0.f, 0.f, 0.f, 0.f}; acc[i][j] = z; }

  const int r0 = t >> 2;            // staging row (i=0): 0..63
  const int ko = (t & 3) * 8;       // staging k-offset within BK
  const int kk = (lane >> 4) * 8;   // frag k-offset
  const int rr = lane & 15;         // frag row/col within 16

  for (int k0 = 0; k0 < K; k0 += 32) {
#pragma unroll
    for (int i = 0; i < 2; ++i) {
      int row = r0 + i * 64;
      gload_lds16(A  + (size_t)(m0 + row) * K + (k0 + ko), As + row * 32 + ko);
      gload_lds16(Bm + (size_t)(n0 + row) * K + (k0 + ko), Bs + row * 32 + ko);
    }
    __syncthreads();

    short8 af[4], bfv[4];
#pragma unroll
    for (int mi = 0; mi < 4; ++mi)
      af[mi] = *(const short8*)(As + (wr * 64 + mi * 16 + rr) * 32 + kk);
#pragma unroll
    for (int ni = 0; ni < 4; ++ni)
      bfv[ni] = *(const short8*)(Bs + (wc * 64 + ni * 16 + rr) * 32 + kk);
#pragma unroll
    for (int mi = 0; mi < 4; ++mi)
#pragma unroll
      for (int ni = 0; ni < 4; ++ni)
        mfma_16x16x32_bf16(acc[mi][ni], af[mi], bfv[ni]);
    __syncthreads();
  }

  // epilogue: C/D layout col = lane&15, row = (lane>>4)*4 + reg  [m89-verified]
  const int crow = (lane >> 4) * 4;
  const int ccol = lane & 15;
#pragma unroll
  for (int mi = 0; mi < 4; ++mi) {
#pragma unroll
    for (int ni = 0; ni < 4; ++ni) {
      int col = n0 + wc * 64 + ni * 16 + ccol;
#pragma unroll
      for (int r = 0; r < 4; ++r) {
        int row = m0 + wr * 64 + mi * 16 + crow + r;
        float v = acc[mi][ni][r];
        size_t idx = (size_t)row * Ncols + col;
        if (EPI == 0) {
          Cb[idx] = f2bf(v);
        } else {
          Cf[idx] = v + Dv[col] * X[idx];
        }
      }
    }
  }
}

// ---------- scan pass A: per-chunk carries (zero-init local recurrence) ----------
__global__ __launch_bounds__(512) void scanA(const ushort* __restrict__ Bu,
                                             const float2* __restrict__ lam,
                                             float2* __restrict__ carry)
{
  int n = threadIdx.x;
  int c = blockIdx.x;
  float2 a = lam[n];
  float cr = 0.f, ci = 0.f;
  int base = c * CT;
#pragma unroll 4
  for (int tt = 0; tt < CT; ++tt) {
    const ushort* p = Bu + (size_t)(base + tt) * 1024 + n;
    float br = bf2f(p[0]);
    float bi = bf2f(p[512]);
    float nr = a.x * cr - a.y * ci + br;
    float ni = a.x * ci + a.y * cr + bi;
    cr = nr; ci = ni;
  }
  carry[c * 512 + n] = make_float2(cr, ci);
}

// ---------- scan pass C: serial scan over chunk carries -> prefix (state before chunk) ----------
__global__ __launch_bounds__(512) void scanC(const float2* __restrict__ carry,
                                             const float2* __restrict__ lamT,
                                             float2* __restrict__ prefix)
{
  int n = threadIdx.x;
  float2 aT = lamT[n];
  float gr = 0.f, gi = 0.f;
  for (int c = 0; c < CH; ++c) {
    prefix[c * 512 + n] = make_float2(gr, gi);
    float2 cc = carry[c * 512 + n];
    float nr = aT.x * gr - aT.y * gi + cc.x;
    float ni = aT.x * gi + aT.y * gr + cc.y;
    gr = nr; gi = ni;
  }
}

// ---------- scan pass B: full recurrence from prefix init, overwrite Bu with h (bf16) ----------
__global__ __launch_bounds__(512) void scanB(ushort* __restrict__ Bu,
                                             const float2* __restrict__ lam,
                                             const float2* __restrict__ prefix)
{
  int n = threadIdx.x;
  int c = blockIdx.x;
  float2 a = lam[n];
  float2 g = prefix[c * 512 + n];
  float hr = g.x, hi = g.y;
  int base = c * CT;
#pragma unroll 4
  for (int tt = 0; tt < CT; ++tt) {
    ushort* p = Bu + (size_t)(base + tt) * 1024 + n;
    float br = bf2f(p[0]);
    float bi = bf2f(p[512]);
    float nr = a.x * hr - a.y * hi + br;
    float ni = a.x * hi + a.y * hr + bi;
    hr = nr; hi = ni;
    p[0]   = f2bf(hr);
    p[512] = f2bf(hi);
  }
}

extern "C" void kernel_launch(void* const* d_in, const int* in_sizes, int n_in,
                              void* d_out, int out_size, void* d_ws, size_t ws_size,
                              hipStream_t stream)
{
  const float* x         = (const float*)d_in[0];
  const float* state_re  = (const float*)d_in[1];
  const float* state_im  = (const float*)d_in[2];
  const float* nu_log    = (const float*)d_in[3];
  const float* theta_log = (const float*)d_in[4];
  const float* gamma_log = (const float*)d_in[5];
  const float* B_re      = (const float*)d_in[6];
  const float* B_im      = (const float*)d_in[7];
  const float* C_re      = (const float*)d_in[8];
  const float* C_im      = (const float*)d_in[9];
  const float* Dv        = (const float*)d_in[10];
  float* y = (float*)d_out;

  char* ws = (char*)d_ws;
  size_t off = 0;
  float2* lam    = (float2*)(ws + off); off += 4096;
  float2* lamT   = (float2*)(ws + off); off += 4096;
  float2* carry  = (float2*)(ws + off); off += (size_t)CH * NST * sizeof(float2);
  float2* prefix = (float2*)(ws + off); off += (size_t)CH * NST * sizeof(float2);
  ushort* W1 = (ushort*)(ws + off); off += (size_t)2 * NST * HDIM * sizeof(ushort);
  ushort* W2 = (ushort*)(ws + off); off += (size_t)HDIM * 2 * NST * sizeof(ushort);
  ushort* xb = (ushort*)(ws + off); off += (size_t)L_SEQ * HDIM * sizeof(ushort);
  ushort* Bu = (ushort*)(ws + off); off += (size_t)L_SEQ * 2 * NST * sizeof(ushort);

  prep_kernel<<<1, NST, 0, stream>>>(state_re, state_im, nu_log, theta_log, lam, lamT);
  buildW1<<<(NST * HDIM) / 256, 256, 0, stream>>>(B_re, B_im, gamma_log, W1);
  buildW2<<<(NST * HDIM) / 256, 256, 0, stream>>>(C_re, C_im, W2);
  castX<<<(L_SEQ * HDIM) / (256 * 8), 256, 0, stream>>>(x, xb);

  // Bu = x @ W1^T  -> (L, 1024) bf16
  gemm_bt<0><<<dim3(L_SEQ / 128, (2 * NST) / 128), 256, 0, stream>>>(
      xb, W1, Bu, nullptr, nullptr, nullptr, L_SEQ, 2 * NST, HDIM);

  scanA<<<CH, NST, 0, stream>>>(Bu, lam, carry);
  scanC<<<1, NST, 0, stream>>>(carry, lamT, prefix);
  scanB<<<CH, NST, 0, stream>>>(Bu, lam, prefix);

  // y = h @ W2^T + D*x  -> (L, 512) f32
  gemm_bt<1><<<dim3(L_SEQ / 128, HDIM / 128), 256, 0, stream>>>(
      Bu, W2, nullptr, y, Dv, x, L_SEQ, HDIM, 2 * NST);
}